// Round 4
// baseline (90.172 us; speedup 1.0000x reference)
//
#include <hip/hip_runtime.h>

// HEAQNetwork: batched 4-qubit, 3-layer circuit, 16 fp32 complex amps in
// registers. All exact algebraic reductions from R2 kept:
//  * layer 1 = product state (tensor build), layer-1 CNOT chain folded into
//    the build permutation J.
//  * gates on qubit 3 (layers 2,3) and qubit 2 (layer 3) pruned; CNOT(2,3)
//    commutes out; measured ops become Z0 and Z0Z1.
// New in R4 (all-fp32, packed f16 gave no issue-rate win on gfx950):
//  * layer-2 CNOT chain folded into layer-3 pair indices + measurement signs:
//    with sigma = CNOT(0,1).CNOT(1,2) index permutation, layer-3 q0 acts on
//    pairs (i, i^12) (0-branch b3=0), q1 on (i, i^6) (0-branch b2==b3);
//    z0 sign = (-1)^b3, z1 sign = (-1)^b2. Zero data movement for CNOTs.
//  * explicit fmaf: every gate output = 1 mul + 1 fma.

__device__ __forceinline__ float rdlane(float x, int l) {
    return __int_as_float(__builtin_amdgcn_readlane(__float_as_int(x), l));
}

// RX over explicit pair lists: [[c, -i s],[-i s, c]]
__device__ __forceinline__ void rx_p(float (&re)[16], float (&im)[16],
                                     float c, float s,
                                     const int (&lo)[8], const int (&hi)[8]) {
#pragma unroll
    for (int t = 0; t < 8; ++t) {
        const int i = lo[t], j = hi[t];
        float a0r = re[i], a0i = im[i], a1r = re[j], a1i = im[j];
        re[i] = __builtin_fmaf(c, a0r,  s * a1i);
        im[i] = __builtin_fmaf(c, a0i, -(s * a1r));
        re[j] = __builtin_fmaf(c, a1r,  s * a0i);
        im[j] = __builtin_fmaf(c, a1i, -(s * a0r));
    }
}

// RY over explicit pair lists: [[c, -s],[s, c]] (real)
__device__ __forceinline__ void ry_p(float (&re)[16], float (&im)[16],
                                     float c, float s,
                                     const int (&lo)[8], const int (&hi)[8]) {
#pragma unroll
    for (int t = 0; t < 8; ++t) {
        const int i = lo[t], j = hi[t];
        float a0r = re[i], a0i = im[i], a1r = re[j], a1i = im[j];
        re[i] = __builtin_fmaf(c, a0r, -(s * a1r));
        im[i] = __builtin_fmaf(c, a0i, -(s * a1i));
        re[j] = __builtin_fmaf(s, a0r,   c * a1r);
        im[j] = __builtin_fmaf(s, a0i,   c * a1i);
    }
}

__global__ __launch_bounds__(256) void heaq_kernel(
    const float4* __restrict__ x4,
    const float*  __restrict__ w_input,
    const float*  __restrict__ weights,
    const float*  __restrict__ w_output,
    float2*       __restrict__ out2,
    int B)
{
    const int lane = threadIdx.x & 63;

    // ---- batch-uniform RY half-angle sincos: lanes 0..11 compute,
    // readlane broadcasts (before bounds check: all lanes valid). ----
    const float K = 0.07957747154594767f;  // 1/(4*pi)
    float wv  = weights[lane < 12 ? lane : 0];
    float rev = __builtin_amdgcn_fractf(wv * K);
    float sn  = __builtin_amdgcn_sinf(rev);
    float cn  = __builtin_amdgcn_cosf(rev);

    const float cy0 = rdlane(cn, 0), sy0 = rdlane(sn, 0);
    const float cy1 = rdlane(cn, 1), sy1 = rdlane(sn, 1);
    const float cy2 = rdlane(cn, 2), sy2 = rdlane(sn, 2);
    const float cy3 = rdlane(cn, 3), sy3 = rdlane(sn, 3);
    const float cy4 = rdlane(cn, 4), sy4 = rdlane(sn, 4);
    const float cy5 = rdlane(cn, 5), sy5 = rdlane(sn, 5);
    const float cy6 = rdlane(cn, 6), sy6 = rdlane(sn, 6);
    const float cy8 = rdlane(cn, 8), sy8 = rdlane(sn, 8);
    const float cy9 = rdlane(cn, 9), sy9 = rdlane(sn, 9);

    const int b = blockIdx.x * 256 + threadIdx.x;
    if (b >= B) return;

    // ---- RX half-angle cos/sin: theta = atan(u) ----
    float4 xv = x4[b];
    float xs[4] = {xv.x, xv.y, xv.z, xv.w};
    float cx[4], sx[4];
#pragma unroll
    for (int q = 0; q < 4; ++q) {
        float u = xs[q] * w_input[q];
        float r = __builtin_amdgcn_rsqf(__builtin_fmaf(u, u, 1.0f));
        float c = __builtin_amdgcn_sqrtf(__builtin_fmaf(0.5f, r, 0.5f));
        cx[q] = c;
        sx[q] = 0.5f * u * r * __builtin_amdgcn_rcpf(c);
    }

    // ---- Layer 1 product state: v_q = RY RX |0> = (cy*cx + i sy*sx,
    //                                                sy*cx - i cy*sx) ----
    const float cys[4] = {cy0, cy1, cy2, cy3};
    const float sys[4] = {sy0, sy1, sy2, sy3};
    float vr[4][2], vi[4][2];
#pragma unroll
    for (int q = 0; q < 4; ++q) {
        vr[q][0] = cys[q] * cx[q];
        vi[q][0] = sys[q] * sx[q];
        vr[q][1] = sys[q] * cx[q];
        vi[q][1] = -cys[q] * sx[q];
    }
    float p2r[4], p2i[4];
#pragma unroll
    for (int i = 0; i < 4; ++i) {
        const int a = i >> 1, c = i & 1;
        p2r[i] = __builtin_fmaf(vr[0][a], vr[1][c], -(vi[0][a] * vi[1][c]));
        p2i[i] = __builtin_fmaf(vr[0][a], vi[1][c],   vi[0][a] * vr[1][c]);
    }
    float p3r[8], p3i[8];
#pragma unroll
    for (int i = 0; i < 8; ++i) {
        const int h = i >> 1, c = i & 1;
        p3r[i] = __builtin_fmaf(p2r[h], vr[2][c], -(p2i[h] * vi[2][c]));
        p3i[i] = __builtin_fmaf(p2r[h], vi[2][c],   p2i[h] * vr[2][c]);
    }
    // final tensor step, layer-1 CNOT chain folded: amp[J[i]] = p3[h]*v3[c]
    constexpr int J[16] = {0,1,3,2, 7,6,4,5, 15,14,12,13, 8,9,11,10};
    float re[16], im[16];
#pragma unroll
    for (int i = 0; i < 16; ++i) {
        const int h = i >> 1, c = i & 1;
        re[J[i]] = __builtin_fmaf(p3r[h], vr[3][c], -(p3i[h] * vi[3][c]));
        im[J[i]] = __builtin_fmaf(p3r[h], vi[3][c],   p3i[h] * vr[3][c]);
    }

    // ---- pair lists ----
    static constexpr int m8_lo[8]  = {0,1,2,3,4,5,6,7};
    static constexpr int m8_hi[8]  = {8,9,10,11,12,13,14,15};
    static constexpr int m4_lo[8]  = {0,1,2,3,8,9,10,11};
    static constexpr int m4_hi[8]  = {4,5,6,7,12,13,14,15};
    static constexpr int m2_lo[8]  = {0,1,4,5,8,9,12,13};
    static constexpr int m2_hi[8]  = {2,3,6,7,10,11,14,15};
    // layer-3 pairs in sigma-space (L2 CNOTs folded)
    static constexpr int x12_lo[8] = {0,1,2,3,4,5,6,7};
    static constexpr int x12_hi[8] = {12,13,14,15,8,9,10,11};
    static constexpr int x6_lo[8]  = {0,1,2,3,12,13,14,15};
    static constexpr int x6_hi[8]  = {6,7,4,5,10,11,8,9};

    // ---- Layer 2: qubits 0,1,2 (true basis; its CNOTs folded forward) ----
    rx_p(re, im, cx[0], sx[0], m8_lo, m8_hi);
    rx_p(re, im, cx[1], sx[1], m4_lo, m4_hi);
    rx_p(re, im, cx[2], sx[2], m2_lo, m2_hi);
    ry_p(re, im, cy4, sy4, m8_lo, m8_hi);
    ry_p(re, im, cy5, sy5, m4_lo, m4_hi);
    ry_p(re, im, cy6, sy6, m2_lo, m2_hi);

    // ---- Layer 3: qubits 0,1 in sigma-space ----
    rx_p(re, im, cx[0], sx[0], x12_lo, x12_hi);
    rx_p(re, im, cx[1], sx[1], x6_lo,  x6_hi);
    ry_p(re, im, cy8, sy8, x12_lo, x12_hi);
    ry_p(re, im, cy9, sy9, x6_lo,  x6_hi);

    // ---- Measurement in sigma-space: z0 ~ (-1)^b3, z1 ~ (-1)^b2 ----
    float p[16];
#pragma unroll
    for (int i = 0; i < 16; ++i)
        p[i] = __builtin_fmaf(re[i], re[i], im[i] * im[i]);
    float S0 = (p[0] + p[1]) + (p[2]  + p[3]);    // b3=0,b2=0
    float S1 = (p[4] + p[5]) + (p[6]  + p[7]);    // b3=0,b2=1
    float S2 = (p[8] + p[9]) + (p[10] + p[11]);   // b3=1,b2=0
    float S3 = (p[12]+ p[13])+ (p[14] + p[15]);   // b3=1,b2=1
    float z0 = (S0 + S1) - (S2 + S3);
    float z1 = (S0 + S2) - (S1 + S3);

    float hw0 = 0.5f * w_output[0], hw1 = 0.5f * w_output[1];
    out2[b] = make_float2(__builtin_fmaf(z0, hw0, hw0),
                          __builtin_fmaf(z1, hw1, hw1));
}

extern "C" void kernel_launch(void* const* d_in, const int* in_sizes, int n_in,
                              void* d_out, int out_size, void* d_ws, size_t ws_size,
                              hipStream_t stream) {
    const float* x        = (const float*)d_in[0];
    const float* w_input  = (const float*)d_in[1];
    const float* weights  = (const float*)d_in[2];
    const float* w_output = (const float*)d_in[3];
    float* out = (float*)d_out;

    const int B = in_sizes[0] / 4;

    heaq_kernel<<<(B + 255) / 256, 256, 0, stream>>>(
        (const float4*)x, w_input, weights, w_output, (float2*)out, B);
}